// Round 7
// baseline (170.333 us; speedup 1.0000x reference)
//
#include <hip/hip_runtime.h>
#include <cstddef>
#include <cstdint>

// B=8192, T=512, I=4, H=32, O=4 — 2-layer tanh RNN + linear head, fp32 I/O.
constexpr int kB = 8192, kT = 512, kI = 4, kH = 32, kO = 4;

typedef _Float16 f16x8 __attribute__((ext_vector_type(8)));
typedef float    f32x4 __attribute__((ext_vector_type(4)));

#define MFMA(a, b, c) __builtin_amdgcn_mfma_f32_16x16x32_f16((a), (b), (c), 0, 0, 0)

// Barrier that waits ONLY on LDS ops (lgkmcnt), leaving global loads/stores in
// flight (the __syncthreads() lowering drains vmcnt(0) too — that full drain
// was costing ~400 cy/step here). Pattern proven in the 8-phase GEMM template.
__device__ __forceinline__ void bar_lds() {
    asm volatile("s_waitcnt lgkmcnt(0)" ::: "memory");
    __builtin_amdgcn_s_barrier();
    asm volatile("" ::: "memory");
}

__device__ __forceinline__ float fast_tanh(float x) {
    // tanh(x) = 1 - 2/(e^{2x}+1); exp2-based, saturates correctly, rel err ~1e-6
    float e = __builtin_amdgcn_exp2f(x * 2.8853900817779268f);
    return 1.0f - 2.0f * __builtin_amdgcn_rcpf(e + 1.0f);
}

__device__ __forceinline__ float4 ld4(const float* p) { return *(const float4*)p; }

// A/B fragment from two float4s: elems 0-3 = k {4g..4g+3}, 4-7 = k {16+4g..}.
__device__ __forceinline__ f16x8 pack_frag(float4 lo, float4 hi) {
    f16x8 r;
    r[0] = (_Float16)lo.x; r[1] = (_Float16)lo.y;
    r[2] = (_Float16)lo.z; r[3] = (_Float16)lo.w;
    r[4] = (_Float16)hi.x; r[5] = (_Float16)hi.y;
    r[6] = (_Float16)hi.z; r[7] = (_Float16)hi.w;
    return r;
}

// D-tile regs -> next-step B k-slots; pure per-lane (4x v_cvt_pkrtz).
__device__ __forceinline__ f16x8 pack_state(f32x4 a, f32x4 b) {
    union { f16x8 v; uint32_t u[4]; } r;
    r.u[0] = __builtin_bit_cast(uint32_t, __builtin_amdgcn_cvt_pkrtz(a[0], a[1]));
    r.u[1] = __builtin_bit_cast(uint32_t, __builtin_amdgcn_cvt_pkrtz(a[2], a[3]));
    r.u[2] = __builtin_bit_cast(uint32_t, __builtin_amdgcn_cvt_pkrtz(b[0], b[1]));
    r.u[3] = __builtin_bit_cast(uint32_t, __builtin_amdgcn_cvt_pkrtz(b[2], b[3]));
    return r.v;
}

// Producer/consumer split: wave 0 = layer 0, wave 1 = layer 1 + head.
// h0 crosses via double-buffered LDS; barriers wait lgkmcnt only, so the x
// prefetch (4-deep) and output stores stay in flight across steps.
__global__ __launch_bounds__(128, 1) void rnn2_split2(
    const float* __restrict__ X,
    const float* __restrict__ W_ih0, const float* __restrict__ W_hh0,
    const float* __restrict__ b_ih0, const float* __restrict__ b_hh0,
    const float* __restrict__ W_ih1, const float* __restrict__ W_hh1,
    const float* __restrict__ b_ih1, const float* __restrict__ b_hh1,
    const float* __restrict__ W_ll, const float* __restrict__ b_ll,
    float* __restrict__ out)
{
    const int  tid = threadIdx.x;
    const int  wid = tid >> 6;       // 0 = L0 producer, 1 = L1+head consumer
    const int  l   = tid & 63;
    const int  c   = l & 15;         // batch col within tile / A row m
    const int  g   = l >> 4;         // k-group
    const bool g0  = (g == 0);
    const int  b   = blockIdx.x * 16 + c;
    const int  k0  = 4 * g;

    __shared__ uint4 h0buf[2][64];   // double-buffered h0 B-fragments

    const float4 z4 = make_float4(0.f, 0.f, 0.f, 0.f);
    union { f16x8 v; uint32_t u[4]; } zz;
    zz.u[0] = zz.u[1] = zz.u[2] = zz.u[3] = 0u;

    if (wid == 0) {
        // ================= producer: layer 0 =================
        const float* wp = W_hh0 + c * kH;
        const f16x8 Ahh0_0 = pack_frag(ld4(wp + k0), ld4(wp + 16 + k0));
        wp = W_hh0 + (c + 16) * kH;
        const f16x8 Ahh0_1 = pack_frag(ld4(wp + k0), ld4(wp + 16 + k0));
        const f16x8 Aih0_0 = pack_frag(g0 ? ld4(W_ih0 + c * kI) : z4, z4);
        const f16x8 Aih0_1 = pack_frag(g0 ? ld4(W_ih0 + (c + 16) * kI) : z4, z4);

        f32x4 bias0_0, bias0_1;
#pragma unroll
        for (int r = 0; r < 4; ++r) {
            bias0_0[r] = b_ih0[k0 + r]      + b_hh0[k0 + r];
            bias0_1[r] = b_ih0[16 + k0 + r] + b_hh0[16 + k0 + r];
        }

        f16x8 Bh0 = zz.v;
        f32x4 xc0, xc1;
        const float* xp = X + (size_t)b * (kT * kI);

        float4 xv0 = ld4(xp);
        float4 xv1 = ld4(xp + 1 * kI);
        float4 xv2 = ld4(xp + 2 * kI);
        float4 xcur[4];
#pragma unroll
        for (int u = 0; u < 4; ++u) xcur[u] = ld4(xp + (3 + u) * kI);

        {   // xc[0] = W_ih0·x0 + b0
            union { f16x8 v; uint32_t u[4]; } bx;
            bx.u[0] = g0 ? __builtin_bit_cast(uint32_t, __builtin_amdgcn_cvt_pkrtz(xv0.x, xv0.y)) : 0u;
            bx.u[1] = g0 ? __builtin_bit_cast(uint32_t, __builtin_amdgcn_cvt_pkrtz(xv0.z, xv0.w)) : 0u;
            bx.u[2] = 0u; bx.u[3] = 0u;
            xc0 = MFMA(Aih0_0, bx.v, bias0_0);
            xc1 = MFMA(Aih0_1, bx.v, bias0_1);
        }

        // One L0 iteration: consumes Bh0 (h0[i-1]), xc[i]; produces h0[i] into
        // h0buf[par]; prepares xc[i+1] from xn = x[i+1].
        auto stepA = [&](float4 xn, int par) {
            union { f16x8 v; uint32_t u[4]; } bx;
            bx.u[0] = g0 ? __builtin_bit_cast(uint32_t, __builtin_amdgcn_cvt_pkrtz(xn.x, xn.y)) : 0u;
            bx.u[1] = g0 ? __builtin_bit_cast(uint32_t, __builtin_amdgcn_cvt_pkrtz(xn.z, xn.w)) : 0u;
            bx.u[2] = 0u; bx.u[3] = 0u;

            f32x4 a0 = MFMA(Ahh0_0, Bh0, xc0);
            f32x4 a1 = MFMA(Ahh0_1, Bh0, xc1);
            xc0 = MFMA(Aih0_0, bx.v, bias0_0);
            xc1 = MFMA(Aih0_1, bx.v, bias0_1);

            f32x4 t0, t1;
#pragma unroll
            for (int r = 0; r < 4; ++r) { t0[r] = fast_tanh(a0[r]); t1[r] = fast_tanh(a1[r]); }
            Bh0 = pack_state(t0, t1);
            h0buf[par][l] = __builtin_bit_cast(uint4, Bh0);
        };

        stepA(xv1, 0); bar_lds();   // i = 0
        stepA(xv2, 1); bar_lds();   // i = 1

        for (int tb = 0; tb < kT / 4; ++tb) {
            const int t0b = 2 + tb * 4;
            float4 xnxt[4];
#pragma unroll
            for (int u = 0; u < 4; ++u) {
                int idx = t0b + 5 + u;
                idx = idx < kT ? idx : (kT - 1);
                xnxt[u] = ld4(xp + idx * kI);
            }
            stepA(xcur[0], 0); bar_lds();
            stepA(xcur[1], 1); bar_lds();
            stepA(xcur[2], 0); bar_lds();
            stepA(xcur[3], 1); bar_lds();
#pragma unroll
            for (int u = 0; u < 4; ++u) xcur[u] = xnxt[u];
        }
    } else {
        // ================= consumer: layer 1 + head =================
        const float* wp = W_ih1 + c * kH;
        const f16x8 Aih1_0 = pack_frag(ld4(wp + k0), ld4(wp + 16 + k0));
        wp = W_ih1 + (c + 16) * kH;
        const f16x8 Aih1_1 = pack_frag(ld4(wp + k0), ld4(wp + 16 + k0));
        wp = W_hh1 + c * kH;
        const f16x8 Ahh1_0 = pack_frag(ld4(wp + k0), ld4(wp + 16 + k0));
        wp = W_hh1 + (c + 16) * kH;
        const f16x8 Ahh1_1 = pack_frag(ld4(wp + k0), ld4(wp + 16 + k0));
        const f16x8 All = (c < kO)
            ? pack_frag(ld4(W_ll + c * kH + k0), ld4(W_ll + c * kH + 16 + k0))
            : pack_frag(z4, z4);

        f32x4 bias1_0, bias1_1, biasll;
#pragma unroll
        for (int r = 0; r < 4; ++r) {
            bias1_0[r] = b_ih1[k0 + r]      + b_hh1[k0 + r];
            bias1_1[r] = b_ih1[16 + k0 + r] + b_hh1[16 + k0 + r];
            biasll[r]  = g0 ? b_ll[r] : 0.f;
        }

        f16x8 Bh1 = zz.v;   // h1[i-2] at iteration entry
        float* op = out + (size_t)b * (kT * kO);

        // One L1 iteration at pipeline index i: head emits step i-2 from Bh1;
        // consumes h0[i-1] from h0buf[par]; produces h1[i-1].
        auto stepB = [&](int par, float* sp) {
            const f16x8 Bh0p = __builtin_bit_cast(f16x8, h0buf[par][l]);
            f32x4 o  = MFMA(All, Bh1, biasll);          // head, step i-2
            f32x4 c0 = MFMA(Aih1_0, Bh0p, bias1_0);
            f32x4 c1 = MFMA(Aih1_1, Bh0p, bias1_1);
            c0 = MFMA(Ahh1_0, Bh1, c0);
            c1 = MFMA(Ahh1_1, Bh1, c1);

            f32x4 u0, u1;
#pragma unroll
            for (int r = 0; r < 4; ++r) { u0[r] = fast_tanh(c0[r]); u1[r] = fast_tanh(c1[r]); }
            Bh1 = pack_state(u0, u1);
            if (sp && g0) *(float4*)sp = make_float4(o[0], o[1], o[2], o[3]);
        };

        stepB(1, nullptr);   // i = 0: reads uninit buf[1] -> result discarded
        Bh1 = zz.v;          // enforce h1[-1] = 0
        bar_lds();
        stepB(0, nullptr);   // i = 1: h0[0] -> h1[0]
        bar_lds();

        for (int tb = 0; tb < kT / 4; ++tb) {
            const int t0b = 2 + tb * 4;
            stepB(1, op + (size_t)(t0b - 2) * kO); bar_lds();
            stepB(0, op + (size_t)(t0b - 1) * kO); bar_lds();
            stepB(1, op + (size_t)(t0b + 0) * kO); bar_lds();
            stepB(0, op + (size_t)(t0b + 1) * kO); bar_lds();
        }
    }
}

extern "C" void kernel_launch(void* const* d_in, const int* in_sizes, int n_in,
                              void* d_out, int out_size, void* d_ws, size_t ws_size,
                              hipStream_t stream) {
    const float* X     = (const float*)d_in[0];
    const float* W_ih0 = (const float*)d_in[1];
    const float* W_hh0 = (const float*)d_in[2];
    const float* b_ih0 = (const float*)d_in[3];
    const float* b_hh0 = (const float*)d_in[4];
    const float* W_ih1 = (const float*)d_in[5];
    const float* W_hh1 = (const float*)d_in[6];
    const float* b_ih1 = (const float*)d_in[7];
    const float* b_hh1 = (const float*)d_in[8];
    const float* W_ll  = (const float*)d_in[9];
    const float* b_ll  = (const float*)d_in[10];
    float* out = (float*)d_out;

    rnn2_split2<<<dim3(kB / 16), dim3(128), 0, stream>>>(
        X, W_ih0, W_hh0, b_ih0, b_hh0, W_ih1, W_hh1, b_ih1, b_hh1, W_ll, b_ll, out);
}

// Round 8
// 124.111 us; speedup vs baseline: 1.3724x; 1.3724x over previous
//
#include <hip/hip_runtime.h>
#include <cstddef>
#include <cstdint>

// B=8192, T=512, I=4, H=32, O=4 — 2-layer tanh RNN + linear head, fp32 I/O.
constexpr int kB = 8192, kT = 512, kI = 4, kH = 32, kO = 4;

typedef _Float16 f16x8 __attribute__((ext_vector_type(8)));
typedef float    f32x4 __attribute__((ext_vector_type(4)));

#define MFMA(a, b, c) __builtin_amdgcn_mfma_f32_16x16x32_f16((a), (b), (c), 0, 0, 0)

// Barrier waiting on LDS ops only (global loads/stores stay in flight).
__device__ __forceinline__ void bar_lds() {
    asm volatile("s_waitcnt lgkmcnt(0)" ::: "memory");
    __builtin_amdgcn_s_barrier();
    __builtin_amdgcn_sched_barrier(0);
}

__device__ __forceinline__ float fast_tanh(float x) {
    float e = __builtin_amdgcn_exp2f(x * 2.8853900817779268f);  // e^{2x}
    return 1.0f - 2.0f * __builtin_amdgcn_rcpf(e + 1.0f);
}

__device__ __forceinline__ float4 ld4(const float* p) { return *(const float4*)p; }

// A/B fragment from two float4s: elems 0-3 = k {4g..4g+3}, 4-7 = k {16+4g..}.
__device__ __forceinline__ f16x8 pack_frag(float4 lo, float4 hi) {
    f16x8 r;
    r[0] = (_Float16)lo.x; r[1] = (_Float16)lo.y;
    r[2] = (_Float16)lo.z; r[3] = (_Float16)lo.w;
    r[4] = (_Float16)hi.x; r[5] = (_Float16)hi.y;
    r[6] = (_Float16)hi.z; r[7] = (_Float16)hi.w;
    return r;
}

// Assemble a B-operand fragment from two uint2 halves (k 0-15 | k 16-31).
__device__ __forceinline__ f16x8 asm_frag(uint2 lo, uint2 hi) {
    union { f16x8 v; uint2 p[2]; } r;
    r.p[0] = lo; r.p[1] = hi;
    return r.v;
}

// One D-half-tile (4 fp32 rows) -> 8B of B k-slots (2x v_cvt_pkrtz).
__device__ __forceinline__ uint2 pack_half(f32x4 t) {
    uint2 r;
    r.x = __builtin_bit_cast(uint32_t, __builtin_amdgcn_cvt_pkrtz(t[0], t[1]));
    r.y = __builtin_bit_cast(uint32_t, __builtin_amdgcn_cvt_pkrtz(t[2], t[3]));
    return r;
}

// x[t] as B-fragment (k=0..3 live on lane-group 0 only).
__device__ __forceinline__ f16x8 bxpack(float4 xn, bool g0) {
    union { f16x8 v; uint32_t u[4]; } bx;
    bx.u[0] = g0 ? __builtin_bit_cast(uint32_t, __builtin_amdgcn_cvt_pkrtz(xn.x, xn.y)) : 0u;
    bx.u[1] = g0 ? __builtin_bit_cast(uint32_t, __builtin_amdgcn_cvt_pkrtz(xn.z, xn.w)) : 0u;
    bx.u[2] = 0u; bx.u[3] = 0u;
    return bx.v;
}

// 4-wave role split per 16-batch tile:
//   wave0 (A0): h0 rows 0-15    wave1 (A1): h0 rows 16-31
//   wave2 (B0): h1 rows 0-15 + head   wave3 (B1): h1 rows 16-31
// Each wave: 2-3 MFMA + 4 tanh per step; halves exchanged via double-buffered
// LDS (8B/lane). 2048 waves total -> 2 waves/SIMD from different blocks, so
// dependency stalls of one pipeline are filled by the other.
// Pipeline index i: A computes h0[i]; B computes h1[i-1]; head emits step i-2.
__global__ __launch_bounds__(256, 2) void rnn2_quad(
    const float* __restrict__ X,
    const float* __restrict__ W_ih0, const float* __restrict__ W_hh0,
    const float* __restrict__ b_ih0, const float* __restrict__ b_hh0,
    const float* __restrict__ W_ih1, const float* __restrict__ W_hh1,
    const float* __restrict__ b_ih1, const float* __restrict__ b_hh1,
    const float* __restrict__ W_ll, const float* __restrict__ b_ll,
    float* __restrict__ out)
{
    const int  tid  = threadIdx.x;
    const int  wid  = tid >> 6;        // 0,1 = L0 halves; 2,3 = L1 halves
    const int  half = wid & 1;         // 0: rows 0-15, 1: rows 16-31
    const int  isB  = wid >> 1;
    const int  l    = tid & 63;
    const int  c    = l & 15;          // batch col within tile
    const int  g    = l >> 4;          // k-group
    const bool g0   = (g == 0);
    const int  b    = blockIdx.x * 16 + c;
    const int  k0   = 4 * g;
    const int  ro   = half * 16;       // row offset of this wave's half

    __shared__ uint2 h0buf[2][2][64];  // [step parity][half][lane]
    __shared__ uint2 h1buf[2][2][64];

    // zero-init both parities (h0[-1]=h1[-1]=h1[-2]=0 fall out of this)
    h0buf[tid >> 7][(tid >> 6) & 1][tid & 63] = make_uint2(0u, 0u);
    h1buf[tid >> 7][(tid >> 6) & 1][tid & 63] = make_uint2(0u, 0u);
    __syncthreads();

    const float4 z4 = make_float4(0.f, 0.f, 0.f, 0.f);

    if (isB == 0) {
        // ======== A-wave: layer 0, rows ro..ro+15 ========
        const float* wp = W_hh0 + (c + ro) * kH;
        const f16x8 Ahh = pack_frag(ld4(wp + k0), ld4(wp + 16 + k0));
        const f16x8 Aih = pack_frag(g0 ? ld4(W_ih0 + (c + ro) * kI) : z4, z4);
        f32x4 bias0;
#pragma unroll
        for (int r = 0; r < 4; ++r) bias0[r] = b_ih0[ro + k0 + r] + b_hh0[ro + k0 + r];

        uint2 myh = make_uint2(0u, 0u);   // own half of h0[i-1] (k-slots)
        f32x4 xc;                          // xc[i] = W_ih0·x[i] + b0 (this half)
        const float* xp = X + (size_t)b * (kT * kI);

        float4 xv0 = ld4(xp);
        float4 xv1 = ld4(xp + 1 * kI);
        float4 xv2 = ld4(xp + 2 * kI);
        float4 xcur[4];
#pragma unroll
        for (int u = 0; u < 4; ++u) xcur[u] = ld4(xp + (3 + u) * kI);
        xc = MFMA(Aih, bxpack(xv0, g0), bias0);

        auto stepA = [&](float4 xn, int i) {
            const int rp = (i - 1) & 1, wpar = i & 1;
            uint2 sib = h0buf[rp][half ^ 1][l];          // sibling half (ds_read)
            f32x4 xcn = MFMA(Aih, bxpack(xn, g0), bias0); // independent; covers read
            f16x8 Bh0 = half == 0 ? asm_frag(myh, sib) : asm_frag(sib, myh);
            f32x4 a = MFMA(Ahh, Bh0, xc);
            f32x4 t;
#pragma unroll
            for (int r = 0; r < 4; ++r) t[r] = fast_tanh(a[r]);
            myh = pack_half(t);
            h0buf[wpar][half][l] = myh;
            xc = xcn;
        };

        stepA(xv1, 0); bar_lds();   // i = 0
        stepA(xv2, 1); bar_lds();   // i = 1
        for (int tb = 0; tb < 128; ++tb) {
            const int i0 = 2 + tb * 4;
            float4 xnxt[4];
#pragma unroll
            for (int u = 0; u < 4; ++u) {
                int idx = i0 + 5 + u;
                idx = idx < kT ? idx : (kT - 1);
                xnxt[u] = ld4(xp + idx * kI);
            }
#pragma unroll
            for (int u = 0; u < 4; ++u) { stepA(xcur[u], i0 + u); bar_lds(); }
#pragma unroll
            for (int u = 0; u < 4; ++u) xcur[u] = xnxt[u];
        }
    } else {
        // ======== B-wave: layer 1 rows ro..ro+15 (+ head on half 0) ========
        const float* wp = W_ih1 + (c + ro) * kH;
        const f16x8 Aih1 = pack_frag(ld4(wp + k0), ld4(wp + 16 + k0));
        wp = W_hh1 + (c + ro) * kH;
        const f16x8 Ahh1 = pack_frag(ld4(wp + k0), ld4(wp + 16 + k0));
        const f16x8 All = (half == 0 && c < kO)
            ? pack_frag(ld4(W_ll + c * kH + k0), ld4(W_ll + c * kH + 16 + k0))
            : pack_frag(z4, z4);

        f32x4 bias1, biasll;
#pragma unroll
        for (int r = 0; r < 4; ++r) {
            bias1[r]  = b_ih1[ro + k0 + r] + b_hh1[ro + k0 + r];
            biasll[r] = g0 ? b_ll[r] : 0.f;
        }

        uint2 myh1 = make_uint2(0u, 0u);  // own half of h1[i-2]
        float* op = out + (size_t)b * (kT * kO);

        auto stepB = [&](int i, bool store) {
            const int rp = (i - 1) & 1, wpar = i & 1;
            uint2 h0lo = h0buf[rp][0][l];
            uint2 h0hi = h0buf[rp][1][l];
            uint2 sib1 = h1buf[rp][half ^ 1][l];
            f16x8 Bh0 = asm_frag(h0lo, h0hi);
            f16x8 Bh1 = half == 0 ? asm_frag(myh1, sib1) : asm_frag(sib1, myh1);
            f32x4 o;
            if (half == 0) o = MFMA(All, Bh1, biasll);   // head, step i-2
            f32x4 cc = MFMA(Aih1, Bh0, bias1);
            cc = MFMA(Ahh1, Bh1, cc);
            f32x4 t;
#pragma unroll
            for (int r = 0; r < 4; ++r) t[r] = fast_tanh(cc[r]);
            myh1 = pack_half(t);
            h1buf[wpar][half][l] = myh1;
            if (store && half == 0 && g0)
                *(float4*)(op + (size_t)(i - 2) * kO) = make_float4(o[0], o[1], o[2], o[3]);
        };

        bar_lds();                    // i = 0: buffers already zero; just sync
        stepB(1, false); bar_lds();   // i = 1: h1[0] from h0[0], h1[-1]=0
        for (int tb = 0; tb < 128; ++tb) {
            const int i0 = 2 + tb * 4;
#pragma unroll
            for (int u = 0; u < 4; ++u) { stepB(i0 + u, true); bar_lds(); }
        }
    }
}

extern "C" void kernel_launch(void* const* d_in, const int* in_sizes, int n_in,
                              void* d_out, int out_size, void* d_ws, size_t ws_size,
                              hipStream_t stream) {
    const float* X     = (const float*)d_in[0];
    const float* W_ih0 = (const float*)d_in[1];
    const float* W_hh0 = (const float*)d_in[2];
    const float* b_ih0 = (const float*)d_in[3];
    const float* b_hh0 = (const float*)d_in[4];
    const float* W_ih1 = (const float*)d_in[5];
    const float* W_hh1 = (const float*)d_in[6];
    const float* b_ih1 = (const float*)d_in[7];
    const float* b_hh1 = (const float*)d_in[8];
    const float* W_ll  = (const float*)d_in[9];
    const float* b_ll  = (const float*)d_in[10];
    float* out = (float*)d_out;

    rnn2_quad<<<dim3(kB / 16), dim3(256), 0, stream>>>(
        X, W_ih0, W_hh0, b_ih0, b_hh0, W_ih1, W_hh1, b_ih1, b_hh1, W_ll, b_ll, out);
}